// Round 3
// baseline (173.737 us; speedup 1.0000x reference)
//
#include <hip/hip_runtime.h>
#include <hip/hip_bf16.h>

// Problem constants (fixed by setup_inputs)
#define BB 32
#define NN 2000
#define CC 80
#define NC 160000   // N*C
#define PP 360
#define KK 300
#define NBIN 2048
#define NPART 16     // hist/scan blocks per batch
#define F4PB 2500    // float4 per partial block (NC/4/NPART)
#define CANDCAP 512
#define POOLCAP 4096

// Output layout (f32 elements), harness concat in return order:
// labels [B,K] @0; boxes [B,K,4] @9600; coords [B,K,P,2] @48000; scores [B,K] @6960000
#define OFF_BOXES  (BB*KK)
#define OFF_COORDS (BB*KK + BB*KK*4)
#define OFF_SCORES (BB*KK + BB*KK*4 + BB*KK*PP*2)

__device__ __forceinline__ unsigned flipf(float f) {
    unsigned u = __float_as_uint(f);
    return (u & 0x80000000u) ? ~u : (u | 0x80000000u);
}
__device__ __forceinline__ float unflipf(unsigned k) {
    unsigned u = (k & 0x80000000u) ? (k & 0x7FFFFFFFu) : ~k;
    return __uint_as_float(u);
}

// ---- K1: per-(batch,part) private histogram of key>>21; full overwrite, no atomics/memset ----
extern "C" __global__ __launch_bounds__(256)
void hist1_kernel(const float* __restrict__ logits, unsigned* __restrict__ partial) {
    const int b = blockIdx.y, p = blockIdx.x;
    __shared__ unsigned h[NBIN];
    for (int i = threadIdx.x; i < NBIN; i += 256) h[i] = 0;
    __syncthreads();
    const float4* src = (const float4*)(logits + (size_t)b * NC) + (size_t)p * F4PB;
    for (int i = threadIdx.x; i < F4PB; i += 256) {
        float4 v = src[i];
        atomicAdd(&h[flipf(v.x) >> 21], 1u);
        atomicAdd(&h[flipf(v.y) >> 21], 1u);
        atomicAdd(&h[flipf(v.z) >> 21], 1u);
        atomicAdd(&h[flipf(v.w) >> 21], 1u);
    }
    __syncthreads();
    unsigned* dst = partial + ((size_t)(b * NPART + p)) * NBIN;
    for (int i = threadIdx.x; i < NBIN; i += 256) dst[i] = h[i];
}

// ---- K2: per-batch reduce partials + suffix scan -> selBin/cntAbove; zero hist2 & counters ----
extern "C" __global__ __launch_bounds__(1024)
void selbin_kernel(const unsigned* __restrict__ partial, unsigned* __restrict__ selInfo,
                   unsigned* __restrict__ hist2, unsigned* __restrict__ counters) {
    const int b = blockIdx.x, tid = threadIdx.x;
    __shared__ unsigned suf[NBIN];
    const unsigned* pp = partial + (size_t)b * NPART * NBIN;
    unsigned a0 = 0, a1 = 0;
    for (int p = 0; p < NPART; p++) { a0 += pp[p * NBIN + tid]; a1 += pp[p * NBIN + tid + 1024]; }
    suf[tid] = a0; suf[tid + 1024] = a1;
    __syncthreads();
    for (unsigned off = 1; off < NBIN; off <<= 1) {
        unsigned t0 = suf[tid]        + ((tid + off < NBIN)        ? suf[tid + off]        : 0);
        unsigned t1 = suf[tid + 1024] + ((tid + 1024 + off < NBIN) ? suf[tid + 1024 + off] : 0);
        __syncthreads();
        suf[tid] = t0; suf[tid + 1024] = t1;
        __syncthreads();
    }
    #pragma unroll
    for (int e = 0; e < 2; e++) {
        int bn = tid + e * 1024;
        if (suf[bn] >= KK && (bn == NBIN - 1 || suf[bn + 1] < KK)) {
            selInfo[b * 2 + 0] = (unsigned)bn;
            selInfo[b * 2 + 1] = (bn == NBIN - 1) ? 0u : suf[bn + 1];
        }
    }
    hist2[(size_t)b * NBIN + tid] = 0;
    hist2[(size_t)b * NBIN + tid + 1024] = 0;
    if (tid == 0) { counters[b * 2] = 0; counters[b * 2 + 1] = 0; }
}

// ---- K3: full-chip rescan; definite-top -> cand, boundary bin -> pool + level-2 hist ----
extern "C" __global__ __launch_bounds__(256)
void scan2_kernel(const float* __restrict__ logits, const unsigned* __restrict__ selInfo,
                  unsigned* __restrict__ counters, unsigned* __restrict__ hist2,
                  unsigned* __restrict__ candKey, unsigned* __restrict__ candIdx,
                  unsigned* __restrict__ poolKey, unsigned* __restrict__ poolIdx) {
    const int b = blockIdx.y, p = blockIdx.x;
    const unsigned selBin = selInfo[b * 2];
    const float4* src = (const float4*)(logits + (size_t)b * NC) + (size_t)p * F4PB;
    const unsigned base = (unsigned)p * (F4PB * 4);
    for (int i = threadIdx.x; i < F4PB; i += 256) {
        float4 v = src[i];
        #pragma unroll
        for (int j = 0; j < 4; j++) {
            float x = (j == 0) ? v.x : (j == 1) ? v.y : (j == 2) ? v.z : v.w;
            unsigned key = flipf(x);
            unsigned bin = key >> 21;
            if (bin > selBin) {
                unsigned pos = atomicAdd(&counters[b * 2], 1u);
                if (pos < CANDCAP) {
                    candKey[b * CANDCAP + pos] = key;
                    candIdx[b * CANDCAP + pos] = base + (unsigned)(i * 4 + j);
                }
            } else if (bin == selBin) {
                unsigned pos = atomicAdd(&counters[b * 2 + 1], 1u);
                if (pos < POOLCAP) {
                    poolKey[b * POOLCAP + pos] = key;
                    poolIdx[b * POOLCAP + pos] = base + (unsigned)(i * 4 + j);
                }
                atomicAdd(&hist2[(size_t)b * NBIN + ((key >> 10) & 0x7FFu)], 1u);
            }
        }
    }
}

// ---- K4: per-batch level-2 select + rank-by-comparison + emit labels/scores/boxes/qidx ----
extern "C" __global__ __launch_bounds__(1024)
void final_kernel(const float* __restrict__ boxes, const float* __restrict__ sizes,
                  const unsigned* __restrict__ selInfo, const unsigned* __restrict__ counters,
                  const unsigned* __restrict__ hist2,
                  const unsigned* __restrict__ candKey, const unsigned* __restrict__ candIdx,
                  const unsigned* __restrict__ poolKey, const unsigned* __restrict__ poolIdx,
                  float* __restrict__ out, int* __restrict__ qidx_ws) {
    const int b = blockIdx.x, tid = threadIdx.x;
    __shared__ unsigned suf[NBIN];
    __shared__ unsigned candK[CANDCAP];
    __shared__ unsigned candI[CANDCAP];
    __shared__ unsigned sNC, sSel2;

    suf[tid]        = hist2[(size_t)b * NBIN + tid];
    suf[tid + 1024] = hist2[(size_t)b * NBIN + tid + 1024];
    __syncthreads();
    for (unsigned off = 1; off < NBIN; off <<= 1) {
        unsigned t0 = suf[tid]        + ((tid + off < NBIN)        ? suf[tid + off]        : 0);
        unsigned t1 = suf[tid + 1024] + ((tid + 1024 + off < NBIN) ? suf[tid + 1024 + off] : 0);
        __syncthreads();
        suf[tid] = t0; suf[tid + 1024] = t1;
        __syncthreads();
    }
    const unsigned cntAbove = selInfo[b * 2 + 1];
    const unsigned target = KK - cntAbove;   // >= 1
    #pragma unroll
    for (int e = 0; e < 2; e++) {
        int bn = tid + e * 1024;
        if (suf[bn] >= target && (bn == NBIN - 1 || suf[bn + 1] < target)) sSel2 = (unsigned)bn;
    }
    const unsigned nCandG = min(counters[b * 2], (unsigned)CANDCAP);
    const unsigned nPool  = min(counters[b * 2 + 1], (unsigned)POOLCAP);
    if (tid == 0) sNC = nCandG;
    __syncthreads();
    const unsigned sel2 = sSel2;
    for (unsigned i = tid; i < nCandG; i += 1024) {
        candK[i] = candKey[b * CANDCAP + i];
        candI[i] = candIdx[b * CANDCAP + i];
    }
    __syncthreads();
    for (unsigned i = tid; i < nPool; i += 1024) {
        unsigned key = poolKey[b * POOLCAP + i];
        if (((key >> 10) & 0x7FFu) >= sel2) {
            unsigned pos = atomicAdd(&sNC, 1u);
            if (pos < CANDCAP) { candK[pos] = key; candI[pos] = poolIdx[b * POOLCAP + i]; }
        }
    }
    __syncthreads();
    const unsigned nC = min(sNC, (unsigned)CANDCAP);
    if (tid < nC) {
        unsigned k_i = candK[tid], x_i = candI[tid];
        unsigned long long me = ((unsigned long long)k_i << 32) | (unsigned)~x_i;
        unsigned rank = 0;
        for (unsigned j = 0; j < nC; j++) {
            unsigned long long o = ((unsigned long long)candK[j] << 32) | (unsigned)~candI[j];
            rank += (o > me) ? 1u : 0u;
        }
        if (rank < KK) {
            float logit = unflipf(k_i);
            float score = 1.0f / (1.0f + expf(-logit));
            unsigned q = x_i / CC;
            unsigned cls = x_i - q * CC;
            int ok = b * KK + (int)rank;
            out[ok] = (float)(cls + 1);
            out[OFF_SCORES + ok] = score;
            qidx_ws[ok] = (int)q;
            float s0 = sizes[b * 2 + 0], s1 = sizes[b * 2 + 1];
            float4 bx = ((const float4*)boxes)[(size_t)b * NN + q];  // cx,cy,w,h
            float hw = 0.5f * bx.z, hh = 0.5f * bx.w;
            float4 ob;
            ob.x = (bx.x - hw) * s0;
            ob.y = (bx.y - hh) * s1;
            ob.z = (bx.x + hw) * s0;
            ob.w = (bx.y + hh) * s1;
            ((float4*)(out + OFF_BOXES))[ok] = ob;
        }
    }
}

// ---- K5: coords gather+scale, one float4 per thread, fully coalesced writes ----
extern "C" __global__ __launch_bounds__(256)
void gather_coords_kernel(const float* __restrict__ coords, const float* __restrict__ sizes,
                          const int* __restrict__ qidx_ws, float* __restrict__ out) {
    const unsigned t = blockIdx.x * 256 + threadIdx.x;   // 0 .. B*K*180-1
    const unsigned bk = t / (PP / 2);                    // /180
    const unsigned r  = t - bk * (PP / 2);
    const unsigned b  = bk / KK;
    const int q = qidx_ws[bk];
    const float s0 = sizes[b * 2 + 0], s1 = sizes[b * 2 + 1];
    float4 v = ((const float4*)coords)[(size_t)(b * NN + q) * (PP / 2) + r];
    v.x *= s0; v.y *= s1; v.z *= s0; v.w *= s1;
    ((float4*)(out + OFF_COORDS))[t] = v;
}

extern "C" void kernel_launch(void* const* d_in, const int* in_sizes, int n_in,
                              void* d_out, int out_size, void* d_ws, size_t ws_size,
                              hipStream_t stream) {
    const float* logits = (const float*)d_in[0];   // [B,N,C] f32
    const float* coords = (const float*)d_in[1];   // [B,N,P,2] f32
    const float* boxes  = (const float*)d_in[2];   // [B,N,4] f32
    const float* osize  = (const float*)d_in[3];   // [B,2] f32 (w,h)
    float* out = (float*)d_out;

    // workspace carve-up (u32 words); every word read is written first this call
    unsigned* w = (unsigned*)d_ws;
    unsigned* partial  = w;                                   // B*NPART*NBIN  = 1,048,576
    unsigned* hist2    = partial + (size_t)BB * NPART * NBIN; // B*NBIN        =    65,536
    unsigned* selInfo  = hist2 + (size_t)BB * NBIN;           // B*2
    unsigned* counters = selInfo + BB * 2;                    // B*2
    unsigned* candKey  = counters + BB * 2;                   // B*512
    unsigned* candIdx  = candKey + BB * CANDCAP;              // B*512
    unsigned* poolKey  = candIdx + BB * CANDCAP;              // B*4096
    unsigned* poolIdx  = poolKey + BB * POOLCAP;              // B*4096
    int*      qidx     = (int*)(poolIdx + BB * POOLCAP);      // B*K

    hist1_kernel<<<dim3(NPART, BB), 256, 0, stream>>>(logits, partial);
    selbin_kernel<<<BB, 1024, 0, stream>>>(partial, selInfo, hist2, counters);
    scan2_kernel<<<dim3(NPART, BB), 256, 0, stream>>>(logits, selInfo, counters, hist2,
                                                      candKey, candIdx, poolKey, poolIdx);
    final_kernel<<<BB, 1024, 0, stream>>>(boxes, osize, selInfo, counters, hist2,
                                          candKey, candIdx, poolKey, poolIdx, out, qidx);
    gather_coords_kernel<<<(BB * KK * (PP / 2)) / 256, 256, 0, stream>>>(coords, osize, qidx, out);
}

// Round 4
// 69.594 us; speedup vs baseline: 2.4964x; 2.4964x over previous
//
#include <hip/hip_runtime.h>
#include <hip/hip_bf16.h>

// Problem constants (fixed by setup_inputs)
#define BB 32
#define NN 2000
#define CC 80
#define NC 160000   // N*C
#define PP 360
#define KK 300
#define NBIN 2048
#define NPART 16     // hist/scan blocks per batch
#define F4PB 2500    // float4 per partial block (NC/4/NPART)
#define LCAP 512     // per-block LDS candidate cap (mean ~38, 80 sigma headroom)
#define CANDTOT 2048 // per-batch candidate cap (mean ~600)

// Output layout (f32 elements), harness concat in return order:
// labels [B,K] @0; boxes [B,K,4] @9600; coords [B,K,P,2] @48000; scores [B,K] @6960000
#define OFF_BOXES  (BB*KK)
#define OFF_COORDS (BB*KK + BB*KK*4)
#define OFF_SCORES (BB*KK + BB*KK*4 + BB*KK*PP*2)

__device__ __forceinline__ unsigned flipf(float f) {
    unsigned u = __float_as_uint(f);
    return (u & 0x80000000u) ? ~u : (u | 0x80000000u);
}
__device__ __forceinline__ float unflipf(unsigned k) {
    unsigned u = (k & 0x80000000u) ? (k & 0x7FFFFFFFu) : ~k;
    return __uint_as_float(u);
}

// ---- K1: per-(batch,part) private histogram of key>>21; plain overwrite, LDS atomics only ----
extern "C" __global__ __launch_bounds__(256)
void hist1_kernel(const float* __restrict__ logits, unsigned* __restrict__ partial) {
    const int b = blockIdx.y, p = blockIdx.x;
    __shared__ unsigned h[NBIN];
    for (int i = threadIdx.x; i < NBIN; i += 256) h[i] = 0;
    __syncthreads();
    const float4* src = (const float4*)(logits + (size_t)b * NC) + (size_t)p * F4PB;
    for (int i = threadIdx.x; i < F4PB; i += 256) {
        float4 v = src[i];
        atomicAdd(&h[flipf(v.x) >> 21], 1u);
        atomicAdd(&h[flipf(v.y) >> 21], 1u);
        atomicAdd(&h[flipf(v.z) >> 21], 1u);
        atomicAdd(&h[flipf(v.w) >> 21], 1u);
    }
    __syncthreads();
    unsigned* dst = partial + ((size_t)(b * NPART + p)) * NBIN;
    for (int i = threadIdx.x; i < NBIN; i += 256) dst[i] = h[i];
}

// ---- K2: per-batch reduce partials + suffix scan -> selBin; zero candidate counter ----
extern "C" __global__ __launch_bounds__(1024)
void selbin_kernel(const unsigned* __restrict__ partial, unsigned* __restrict__ selInfo,
                   unsigned* __restrict__ counters) {
    const int b = blockIdx.x, tid = threadIdx.x;
    __shared__ unsigned suf[NBIN];
    const unsigned* pp = partial + (size_t)b * NPART * NBIN;
    unsigned a0 = 0, a1 = 0;
    for (int p = 0; p < NPART; p++) { a0 += pp[p * NBIN + tid]; a1 += pp[p * NBIN + tid + 1024]; }
    suf[tid] = a0; suf[tid + 1024] = a1;
    __syncthreads();
    for (unsigned off = 1; off < NBIN; off <<= 1) {
        unsigned t0 = suf[tid]        + ((tid + off < NBIN)        ? suf[tid + off]        : 0);
        unsigned t1 = suf[tid + 1024] + ((tid + 1024 + off < NBIN) ? suf[tid + 1024 + off] : 0);
        __syncthreads();
        suf[tid] = t0; suf[tid + 1024] = t1;
        __syncthreads();
    }
    #pragma unroll
    for (int e = 0; e < 2; e++) {
        int bn = tid + e * 1024;
        if (suf[bn] >= KK && (bn == NBIN - 1 || suf[bn + 1] < KK)) selInfo[b] = (unsigned)bn;
    }
    if (tid == 0) counters[b] = 0;
}

// ---- K3: full-chip rescan; bin >= selBin -> LDS stage -> one global reserve per block ----
extern "C" __global__ __launch_bounds__(256)
void scan2_kernel(const float* __restrict__ logits, const unsigned* __restrict__ selInfo,
                  unsigned* __restrict__ counters,
                  unsigned* __restrict__ candKey, unsigned* __restrict__ candIdx) {
    const int b = blockIdx.y, p = blockIdx.x;
    const unsigned selBin = selInfo[b];
    __shared__ unsigned lK[LCAP], lI[LCAP];
    __shared__ unsigned lN, gBase;
    if (threadIdx.x == 0) lN = 0;
    __syncthreads();
    const float4* src = (const float4*)(logits + (size_t)b * NC) + (size_t)p * F4PB;
    const unsigned base = (unsigned)p * (F4PB * 4);
    for (int i = threadIdx.x; i < F4PB; i += 256) {
        float4 v = src[i];
        #pragma unroll
        for (int j = 0; j < 4; j++) {
            float x = (j == 0) ? v.x : (j == 1) ? v.y : (j == 2) ? v.z : v.w;
            unsigned key = flipf(x);
            if ((key >> 21) >= selBin) {
                unsigned pos = atomicAdd(&lN, 1u);
                if (pos < LCAP) { lK[pos] = key; lI[pos] = base + (unsigned)(i * 4 + j); }
            }
        }
    }
    __syncthreads();
    const unsigned n = min(lN, (unsigned)LCAP);
    if (threadIdx.x == 0) gBase = atomicAdd(&counters[b], n);
    __syncthreads();
    const unsigned gb = gBase;
    for (unsigned i = threadIdx.x; i < n; i += 256) {
        unsigned pos = gb + i;
        if (pos < CANDTOT) {
            candKey[b * CANDTOT + pos] = lK[i];
            candIdx[b * CANDTOT + pos] = lI[i];
        }
    }
}

// ---- K4: per-batch exact rank-by-comparison over ~600 candidates + emit ----
extern "C" __global__ __launch_bounds__(1024)
void final_kernel(const float* __restrict__ boxes, const float* __restrict__ sizes,
                  const unsigned* __restrict__ counters,
                  const unsigned* __restrict__ candKey, const unsigned* __restrict__ candIdx,
                  float* __restrict__ out, int* __restrict__ qidx_ws) {
    const int b = blockIdx.x, tid = threadIdx.x;
    __shared__ unsigned cK[CANDTOT], cI[CANDTOT];
    const unsigned nC = min(counters[b], (unsigned)CANDTOT);
    for (unsigned i = tid; i < nC; i += 1024) {
        cK[i] = candKey[b * CANDTOT + i];
        cI[i] = candIdx[b * CANDTOT + i];
    }
    __syncthreads();
    for (unsigned s = tid; s < nC; s += 1024) {
        const unsigned k_i = cK[s], x_i = cI[s];
        const unsigned long long me = ((unsigned long long)k_i << 32) | (unsigned)~x_i;
        unsigned rank = 0;
        for (unsigned j = 0; j < nC; j++) {
            unsigned long long o = ((unsigned long long)cK[j] << 32) | (unsigned)~cI[j];
            rank += (o > me) ? 1u : 0u;
        }
        if (rank < KK) {
            float logit = unflipf(k_i);
            float score = 1.0f / (1.0f + expf(-logit));
            unsigned q = x_i / CC;
            unsigned cls = x_i - q * CC;
            int ok = b * KK + (int)rank;
            out[ok] = (float)(cls + 1);
            out[OFF_SCORES + ok] = score;
            qidx_ws[ok] = (int)q;
            float s0 = sizes[b * 2 + 0], s1 = sizes[b * 2 + 1];
            float4 bx = ((const float4*)boxes)[(size_t)b * NN + q];  // cx,cy,w,h
            float hw = 0.5f * bx.z, hh = 0.5f * bx.w;
            float4 ob;
            ob.x = (bx.x - hw) * s0;
            ob.y = (bx.y - hh) * s1;
            ob.z = (bx.x + hw) * s0;
            ob.w = (bx.y + hh) * s1;
            ((float4*)(out + OFF_BOXES))[ok] = ob;
        }
    }
}

// ---- K5: coords gather+scale, one float4 per thread, fully coalesced writes ----
extern "C" __global__ __launch_bounds__(256)
void gather_coords_kernel(const float* __restrict__ coords, const float* __restrict__ sizes,
                          const int* __restrict__ qidx_ws, float* __restrict__ out) {
    const unsigned t = blockIdx.x * 256 + threadIdx.x;   // 0 .. B*K*180-1
    const unsigned bk = t / (PP / 2);                    // /180
    const unsigned r  = t - bk * (PP / 2);
    const unsigned b  = bk / KK;
    const int q = qidx_ws[bk];
    const float s0 = sizes[b * 2 + 0], s1 = sizes[b * 2 + 1];
    float4 v = ((const float4*)coords)[(size_t)(b * NN + q) * (PP / 2) + r];
    v.x *= s0; v.y *= s1; v.z *= s0; v.w *= s1;
    ((float4*)(out + OFF_COORDS))[t] = v;
}

extern "C" void kernel_launch(void* const* d_in, const int* in_sizes, int n_in,
                              void* d_out, int out_size, void* d_ws, size_t ws_size,
                              hipStream_t stream) {
    const float* logits = (const float*)d_in[0];   // [B,N,C] f32
    const float* coords = (const float*)d_in[1];   // [B,N,P,2] f32
    const float* boxes  = (const float*)d_in[2];   // [B,N,4] f32
    const float* osize  = (const float*)d_in[3];   // [B,2] f32 (w,h)
    float* out = (float*)d_out;

    // workspace carve-up (u32 words); every word read is written first this call
    unsigned* w = (unsigned*)d_ws;
    unsigned* partial  = w;                                   // B*NPART*NBIN = 1,048,576
    unsigned* selInfo  = partial + (size_t)BB * NPART * NBIN; // B
    unsigned* counters = selInfo + BB;                        // B
    unsigned* candKey  = counters + BB;                       // B*CANDTOT
    unsigned* candIdx  = candKey + BB * CANDTOT;              // B*CANDTOT
    int*      qidx     = (int*)(candIdx + BB * CANDTOT);      // B*K

    hist1_kernel<<<dim3(NPART, BB), 256, 0, stream>>>(logits, partial);
    selbin_kernel<<<BB, 1024, 0, stream>>>(partial, selInfo, counters);
    scan2_kernel<<<dim3(NPART, BB), 256, 0, stream>>>(logits, selInfo, counters, candKey, candIdx);
    final_kernel<<<BB, 1024, 0, stream>>>(boxes, osize, counters, candKey, candIdx, out, qidx);
    gather_coords_kernel<<<(BB * KK * (PP / 2)) / 256, 256, 0, stream>>>(coords, osize, qidx, out);
}